// Round 1
// baseline (35.041 us; speedup 1.0000x reference)
//
#include <hip/hip_runtime.h>
#include <float.h>

// Problem constants from setup_inputs(): B=16, Q=32, D=256, V=30522, P=8,
// WINDOW_SIZES=[1,3] -> F=3 scores, PROXIMITY=8.
#define B_  16
#define Q_  32
#define D_  256
#define V_  30522
#define F_  3
#define PROX 8

// One block per batch row b. 256 threads = 4 waves.
// Thread tid owns document column d = tid for the gather + prox phases.
__global__ __launch_bounds__(256) void score_kernel(
    const int*   __restrict__ qids,   // [B,Q]
    const float* __restrict__ qw,     // [B,Q]
    const int*   __restrict__ dids,   // [B,D]
    const float* __restrict__ dlog,   // [B,D,V]
    float*       __restrict__ scores) // [B,F]
{
    __shared__ int   s_qid[Q_];
    __shared__ float s_qw[Q_];
    __shared__ int   s_did[D_];
    __shared__ float s_tr[Q_][D_ + 1];   // trans, later overwritten with prox
    __shared__ float s_part[4][F_];

    const int b    = blockIdx.x;
    const int tid  = threadIdx.x;
    const int lane = tid & 63;
    const int wave = tid >> 6;

    if (tid < Q_) { s_qid[tid] = qids[b * Q_ + tid]; s_qw[tid] = qw[b * Q_ + tid]; }
    s_did[tid] = dids[b * D_ + tid];
    __syncthreads();

    // ---- gather: trans[q][d] = qw[q] * dlog[b, d, qid[q]] ----
    {
        const float* base = dlog + (size_t)b * D_ * V_ + (size_t)tid * V_;
        #pragma unroll
        for (int q = 0; q < Q_; ++q) {
            s_tr[q][tid] = base[s_qid[q]] * s_qw[q];
        }
    }
    __syncthreads();

    // ---- s0: sum_q max_d trans ----
    float sum0 = 0.f;
    #pragma unroll
    for (int r = 0; r < 8; ++r) {
        const int q = wave * 8 + r;
        float m = -FLT_MAX;
        for (int d = lane; d < D_; d += 64) m = fmaxf(m, s_tr[q][d]);
        #pragma unroll
        for (int off = 32; off; off >>= 1) m = fmaxf(m, __shfl_xor(m, off));
        sum0 += m;
    }

    // ---- s1: ordered 3-gram on exact ----
    float sum1 = 0.f;
    for (int q = wave; q < Q_ - 2; q += 4) {
        const int qa = s_qid[q], qb = s_qid[q + 1], qc = s_qid[q + 2];
        float m = 0.f;   // entries are >= 0 by construction
        for (int d = lane; d < D_ - 2; d += 64) {
            const float e0 = (qa == s_did[d])     ? s_tr[q][d]         : 0.f;
            const float e1 = (qb == s_did[d + 1]) ? s_tr[q + 1][d + 1] : 0.f;
            const float e2 = (qc == s_did[d + 2]) ? s_tr[q + 2][d + 2] : 0.f;
            const float v  = (e0 > 0.f && e1 > 0.f && e2 > 0.f) ? (e0 + e1 + e2) : 0.f;
            m = fmaxf(m, v);
        }
        #pragma unroll
        for (int off = 32; off; off >>= 1) m = fmaxf(m, __shfl_xor(m, off));
        sum1 += m;
    }

    // ---- prox[q][d] = max_{i<8} exact[q][d+i], computed into registers,
    //      then written back in place over s_tr (barrier-fenced). ----
    float px[Q_];
    const int d0 = tid;
    if (d0 < D_ - PROX + 1) {
        #pragma unroll
        for (int q = 0; q < Q_; ++q) {
            const int qid = s_qid[q];
            float m = -FLT_MAX;
            #pragma unroll
            for (int i = 0; i < PROX; ++i) {
                const float e = (qid == s_did[d0 + i]) ? s_tr[q][d0 + i] : 0.f;
                m = fmaxf(m, e);
            }
            px[q] = m;
        }
    }
    __syncthreads();   // all reads of trans done
    if (d0 < D_ - PROX + 1) {
        #pragma unroll
        for (int q = 0; q < Q_; ++q) s_tr[q][d0] = px[q];
    }
    __syncthreads();   // prox visible everywhere

    // ---- s2: unordered-proximity 3-gram on prox ----
    float sum2 = 0.f;
    for (int q = wave; q < Q_ - 2; q += 4) {
        float m = 0.f;
        for (int d = lane; d < D_ - PROX + 1; d += 64) {
            const float p0 = s_tr[q][d], p1 = s_tr[q + 1][d], p2 = s_tr[q + 2][d];
            const float v  = (p0 > 0.f && p1 > 0.f && p2 > 0.f) ? (p0 + p1 + p2) : 0.f;
            m = fmaxf(m, v);
        }
        #pragma unroll
        for (int off = 32; off; off >>= 1) m = fmaxf(m, __shfl_xor(m, off));
        sum2 += m;
    }

    if (lane == 0) { s_part[wave][0] = sum0; s_part[wave][1] = sum1; s_part[wave][2] = sum2; }
    __syncthreads();
    if (tid == 0) {
        float a0 = 0.f, a1 = 0.f, a2 = 0.f;
        #pragma unroll
        for (int w = 0; w < 4; ++w) { a0 += s_part[w][0]; a1 += s_part[w][1]; a2 += s_part[w][2]; }
        scores[b * F_ + 0] = a0;
        scores[b * F_ + 1] = a1;
        scores[b * F_ + 2] = a2;
    }
}

// Ragged segment-max over passage groups + linear head.
__global__ void finalize_kernel(
    const float* __restrict__ scores,  // [B,F]
    const int*   __restrict__ poff,    // [P+1]
    const float* __restrict__ lw,      // [1,F]
    const float* __restrict__ lb,      // [1]
    float*       __restrict__ out,     // [P]
    int P)
{
    const int p = threadIdx.x;
    if (p < P) {
        const int lo = poff[p], hi = poff[p + 1];
        float m0 = -FLT_MAX, m1 = -FLT_MAX, m2 = -FLT_MAX;
        for (int b = lo; b < hi; ++b) {
            m0 = fmaxf(m0, scores[b * F_ + 0]);
            m1 = fmaxf(m1, scores[b * F_ + 1]);
            m2 = fmaxf(m2, scores[b * F_ + 2]);
        }
        out[p] = m0 * lw[0] + m1 * lw[1] + m2 * lw[2] + lb[0];
    }
}

extern "C" void kernel_launch(void* const* d_in, const int* in_sizes, int n_in,
                              void* d_out, int out_size, void* d_ws, size_t ws_size,
                              hipStream_t stream) {
    const int*   qids = (const int*)  d_in[0];
    const float* qw   = (const float*)d_in[1];
    const int*   dids = (const int*)  d_in[2];
    const float* dlog = (const float*)d_in[3];
    const int*   poff = (const int*)  d_in[4];
    const float* lw   = (const float*)d_in[5];
    const float* lb   = (const float*)d_in[6];
    float* out    = (float*)d_out;
    float* scores = (float*)d_ws;      // [B,F] = 192 bytes

    score_kernel<<<B_, 256, 0, stream>>>(qids, qw, dids, dlog, scores);
    const int P = in_sizes[4] - 1;
    finalize_kernel<<<1, 64, 0, stream>>>(scores, poff, lw, lb, out, P);
}